// Round 9
// baseline (93.561 us; speedup 1.0000x reference)
//
#include <hip/hip_runtime.h>
#include <hip/hip_fp16.h>

typedef __fp16 h2 __attribute__((ext_vector_type(2)));

#if defined(__has_builtin)
#if __has_builtin(__builtin_amdgcn_fdot2)
#define HAVE_FDOT2 1
#endif
#endif

__device__ inline float dot2f(h2 a, h2 b, float acc) {
#ifdef HAVE_FDOT2
    return __builtin_amdgcn_fdot2(a, b, acc, false);
#else
    return acc + (float)a.x * (float)b.x + (float)a.y * (float)b.y;
#endif
}

__device__ inline float wave_sum(float v) {
#pragma unroll
    for (int off = 32; off > 0; off >>= 1) v += __shfl_down(v, off, 64);
    return v;
}

// =============== Kernel 1: prep (2144 blocks x 256) ===============
// blk <2048   : feat group-stat partials (64 groups x 32 chunks of 8192 floats)
// 2048..2111  : dec4 GN+ReLU+GAP -> g_buf
// 2112..2143  : E[c,o] = W_ctrl[o,256:512] . emb[c]
__global__ __launch_bounds__(256) void prep(
    const float* __restrict__ feat, const float* __restrict__ dec4,
    const float* __restrict__ gn_gap_gamma, const float* __restrict__ gn_gap_beta,
    const float* __restrict__ emb, const float* __restrict__ W_ctrl,
    float* __restrict__ partials, float* __restrict__ g_buf,
    float* __restrict__ E_ws) {
    int blk = blockIdx.x;
    int tid = threadIdx.x;
    int wid = tid >> 6, lane = tid & 63;
    if (blk < 2048) {
        int grp = blk >> 5;     // b*16+g
        int chunk = blk & 31;
        const float4* base = (const float4*)(feat + (size_t)grp * 262144 + (size_t)chunk * 8192);
        float sa = 0.f, qa = 0.f, sb = 0.f, qb = 0.f;
#pragma unroll
        for (int i = 0; i < 4; ++i) {
            float4 v = base[i * 256 + tid];
            float4 u = base[(i + 4) * 256 + tid];
            sa += v.x + v.y + v.z + v.w;
            qa += v.x * v.x + v.y * v.y + v.z * v.z + v.w * v.w;
            sb += u.x + u.y + u.z + u.w;
            qb += u.x * u.x + u.y * u.y + u.z * u.z + u.w * u.w;
        }
        __shared__ float ls[4], lq[4];
        float s = wave_sum(sa + sb);
        float q = wave_sum(qa + qb);
        if (lane == 0) { ls[wid] = s; lq[wid] = q; }
        __syncthreads();
        if (tid == 0) {
            partials[blk * 2 + 0] = ls[0] + ls[1] + ls[2] + ls[3];
            partials[blk * 2 + 1] = lq[0] + lq[1] + lq[2] + lq[3];
        }
    } else if (blk < 2112) {
        // ---- dec4 group (b,gi): 32 ch x 256 px, fully parallel ----
        int idx = blk - 2048;            // b*16+gi
        int b = idx >> 4, gi = idx & 15;
        const float* base = dec4 + (size_t)idx * 8192;
        int ch = tid >> 3, sub = tid & 7;     // thread: 32-px slice of channel ch
        const float4* r = (const float4*)(base + ch * 256 + sub * 32);
        float v[32];
        float s = 0.f, q = 0.f;
#pragma unroll
        for (int i = 0; i < 8; ++i) {
            float4 a = r[i];
            v[i * 4 + 0] = a.x; v[i * 4 + 1] = a.y; v[i * 4 + 2] = a.z; v[i * 4 + 3] = a.w;
            s += a.x + a.y + a.z + a.w;
            q += a.x * a.x + a.y * a.y + a.z * a.z + a.w * a.w;
        }
        __shared__ float ls[4], lq[4], bc[2];
        s = wave_sum(s); q = wave_sum(q);
        if (lane == 0) { ls[wid] = s; lq[wid] = q; }
        __syncthreads();
        if (tid == 0) {
            float S = ls[0] + ls[1] + ls[2] + ls[3];
            float Q = lq[0] + lq[1] + lq[2] + lq[3];
            const float inv = 1.f / 8192.f;
            float mu = S * inv;
            float var = Q * inv - mu * mu;
            bc[0] = mu;
            bc[1] = rsqrtf(var + 1e-5f);
        }
        __syncthreads();
        float mu = bc[0], rs = bc[1];
        int c = gi * 32 + ch;
        float sc = rs * gn_gap_gamma[c];
        float sh = gn_gap_beta[c] - mu * sc;
        float acc = 0.f;
#pragma unroll
        for (int i = 0; i < 32; ++i) acc += fmaxf(v[i] * sc + sh, 0.f);
#pragma unroll
        for (int m = 1; m < 8; m <<= 1) acc += __shfl_xor(acc, m, 64);
        if (sub == 0) g_buf[b * 512 + c] = acc * (1.f / 256.f);
    } else {
        // ---- E[c,o] ----
        int c = blk - 2112;
        __shared__ float es[256];
        es[tid] = emb[c * 256 + tid];
        __syncthreads();
        if (tid < 153) {
            const float4* w4 = (const float4*)(W_ctrl + tid * 512 + 256);
            const float4* e4 = (const float4*)es;
            float acc = 0.f;
#pragma unroll 8
            for (int k = 0; k < 64; ++k) {
                float4 a = w4[k], e = e4[k];
                acc += a.x * e.x + a.y * e.y + a.z * e.z + a.w * e.w;
            }
            E_ws[c * 153 + tid] = acc;
        }
    }
}

// =============== Kernel 2: fc (4 blocks x 256) -> packed f16 params ===============
// Per (b,c), 320 bytes: f16[152] (W1|W2|W3|b1|b2), f32 b3 at byte 304.
__global__ __launch_bounds__(256) void fc(
    const float* __restrict__ g_buf, const float* __restrict__ W_gap,
    const float* __restrict__ b_gap, const float* __restrict__ W_ctrl,
    const float* __restrict__ b_ctrl, const float* __restrict__ E_ws,
    unsigned char* __restrict__ pk) {
    int b = blockIdx.x, tid = threadIdx.x;
    __shared__ float gs[512];
    __shared__ float xf[256];
    __shared__ float F[160];
    gs[tid] = g_buf[b * 512 + tid];
    gs[tid + 256] = g_buf[b * 512 + 256 + tid];
    __syncthreads();
    {
        const float4* w = (const float4*)(W_gap + tid * 512);
        const float4* g4 = (const float4*)gs;
        float acc = b_gap[tid];
#pragma unroll 8
        for (int k = 0; k < 128; ++k) {
            float4 wv = w[k], gv = g4[k];
            acc += wv.x * gv.x + wv.y * gv.y + wv.z * gv.z + wv.w * gv.w;
        }
        xf[tid] = acc;
    }
    __syncthreads();
    if (tid < 160) {
        float acc = 0.f;
        if (tid < 153) {
            const float4* w = (const float4*)(W_ctrl + tid * 512);
            const float4* x4 = (const float4*)xf;
#pragma unroll 8
            for (int k = 0; k < 64; ++k) {
                float4 wv = w[k], xv = x4[k];
                acc += wv.x * xv.x + wv.y * xv.y + wv.z * xv.z + wv.w * xv.w;
            }
            acc += b_ctrl[tid];
        }
        F[tid] = acc;
    }
    __syncthreads();
    unsigned char* dst = pk + (size_t)b * 10240;
    for (int c = 0; c < 32; ++c) {
        if (tid < 152) {
            float v = F[tid] + E_ws[c * 153 + tid];
            ((__fp16*)(dst + c * 320))[tid] = (__fp16)v;
        } else if (tid == 152) {
            *(float*)(dst + c * 320 + 304) = F[152] + E_ws[c * 153 + 152];
        }
    }
}

// 8-in/8-out f16 MLP layer for one pixel: xin[4] h2 pairs -> relu -> xout[4] h2
__device__ inline void layer8(const float4 W[8], const float bias[8],
                              const h2 xin[4], h2 xout[4]) {
    float t[8];
#pragma unroll
    for (int o = 0; o < 8; ++o) {
        h2 wa = __builtin_bit_cast(h2, W[o].x), wb = __builtin_bit_cast(h2, W[o].y),
           wc = __builtin_bit_cast(h2, W[o].z), wd = __builtin_bit_cast(h2, W[o].w);
        float s = dot2f(wd, xin[3], dot2f(wc, xin[2], dot2f(wb, xin[1], dot2f(wa, xin[0], bias[o]))));
        t[o] = fmaxf(s, 0.f);
    }
    xout[0] = __builtin_amdgcn_cvt_pkrtz(t[0], t[1]);
    xout[1] = __builtin_amdgcn_cvt_pkrtz(t[2], t[3]);
    xout[2] = __builtin_amdgcn_cvt_pkrtz(t[4], t[5]);
    xout[3] = __builtin_amdgcn_cvt_pkrtz(t[6], t[7]);
}

__device__ inline float layer_out(float4 w3r, float b3v, const h2 z[4]) {
    h2 wa = __builtin_bit_cast(h2, w3r.x), wb = __builtin_bit_cast(h2, w3r.y),
       wc = __builtin_bit_cast(h2, w3r.z), wd = __builtin_bit_cast(h2, w3r.w);
    return dot2f(wd, z[3], dot2f(wc, z[2], dot2f(wb, z[1], dot2f(wa, z[0], b3v))));
}

// =============== Kernel 3: mainK (512 blocks x 512, 8 waves) ===============
// Block = (b, 512-px tile). Wave w owns c in [4w, 4w+4).
__global__ __launch_bounds__(512, 4) void mainK(
    const float* __restrict__ feat, const float* __restrict__ partials,
    const float* __restrict__ gamma, const float* __restrict__ beta,
    const float* __restrict__ W_pre, const float* __restrict__ b_pre,
    const float4* __restrict__ pk, float* __restrict__ out) {
    int blk = blockIdx.x;            // 0..511
    int b = blk >> 7;
    int tid = threadIdx.x;
    int w = tid >> 6, lane = tid & 63;
    int P0 = (blk & 127) << 9;

    __shared__ __align__(16) float smem[4768];  // 19072 B
    float4* pp   = (float4*)smem;               // [0,2560) packed params
    float4* hi_l = (float4*)(smem + 2560);      // [2560,4608) hi f16x8, px-direct
    float2* sch  = (float2*)(smem + 4608);      // 64 x (scale, shift)
    float* mus = smem + 4736;                   // 16
    float* rss = smem + 4752;                   // 16

    const float4* src = pk + (size_t)b * 640;
    for (int i = tid; i < 640; i += 512) pp[i] = src[i];

    if (tid < 16) {
        float s = 0.f, q = 0.f;
#pragma unroll
        for (int cc = 0; cc < 32; ++cc) {
            int idx = ((b * 16 + tid) * 32 + cc) * 2;
            s += partials[idx]; q += partials[idx + 1];
        }
        const float inv = 1.f / 262144.f;
        float mu = s * inv;
        float var = q * inv - mu * mu;
        mus[tid] = mu; rss[tid] = rsqrtf(var + 1e-5f);
    }
    __syncthreads();
    if (tid < 64) {
        float mu = mus[tid >> 2], rs = rss[tid >> 2];
        float sg = rs * gamma[tid];
        sch[tid] = make_float2(sg, beta[tid] - mu * sg);
    }
    __syncthreads();

    // head: 1 px per thread -> hi_l[tid]
    {
        float hi[8];
#pragma unroll
        for (int o = 0; o < 8; ++o) hi[o] = b_pre[o];
        const float* fb = feat + ((size_t)b << 22) + P0 + tid;
#pragma unroll
        for (int ch = 0; ch < 64; ++ch) {
            float v = fb[(size_t)ch << 16];
            float2 ss = sch[ch];
            float pre = fmaxf(v * ss.x + ss.y, 0.f);
#pragma unroll
            for (int o = 0; o < 8; ++o) hi[o] += W_pre[o * 64 + ch] * pre;
        }
        float4 hq;
        hq.x = __builtin_bit_cast(float, __builtin_amdgcn_cvt_pkrtz(hi[0], hi[1]));
        hq.y = __builtin_bit_cast(float, __builtin_amdgcn_cvt_pkrtz(hi[2], hi[3]));
        hq.z = __builtin_bit_cast(float, __builtin_amdgcn_cvt_pkrtz(hi[4], hi[5]));
        hq.w = __builtin_bit_cast(float, __builtin_amdgcn_cvt_pkrtz(hi[6], hi[7]));
        hi_l[tid] = hq;
    }
    __syncthreads();

    // MLP: wave w -> 4 c over 512 px; 2 j-iters x 4 px per lane, float4 stores
    float* ob = out + ((size_t)b << 21) + P0;
#pragma unroll 1
    for (int kk = 0; kk < 4; ++kk) {
        int c = (w << 2) + kk;
        const float4* Pc = pp + c * 20;
        float4 w1r[8], w2r[8];
#pragma unroll
        for (int o = 0; o < 8; ++o) w1r[o] = Pc[o];
#pragma unroll
        for (int o = 0; o < 8; ++o) w2r[o] = Pc[8 + o];
        float4 w3r = Pc[16];
        float4 b1r = Pc[17];
        float4 b2r = Pc[18];
        float b3v = Pc[19].x;
        float b1f[8], b2f[8];
        { h2 t = __builtin_bit_cast(h2, b1r.x); b1f[0] = t.x; b1f[1] = t.y; }
        { h2 t = __builtin_bit_cast(h2, b1r.y); b1f[2] = t.x; b1f[3] = t.y; }
        { h2 t = __builtin_bit_cast(h2, b1r.z); b1f[4] = t.x; b1f[5] = t.y; }
        { h2 t = __builtin_bit_cast(h2, b1r.w); b1f[6] = t.x; b1f[7] = t.y; }
        { h2 t = __builtin_bit_cast(h2, b2r.x); b2f[0] = t.x; b2f[1] = t.y; }
        { h2 t = __builtin_bit_cast(h2, b2r.y); b2f[2] = t.x; b2f[3] = t.y; }
        { h2 t = __builtin_bit_cast(h2, b2r.z); b2f[4] = t.x; b2f[5] = t.y; }
        { h2 t = __builtin_bit_cast(h2, b2r.w); b2f[6] = t.x; b2f[7] = t.y; }

        float* cp = ob + ((size_t)c << 16);
#pragma unroll
        for (int j = 0; j < 2; ++j) {
            int pb = j * 256 + lane * 4;       // pixel base, 4 consecutive px
            float4 h0 = hi_l[pb + 0];
            float4 h1 = hi_l[pb + 1];
            float4 h2v = hi_l[pb + 2];
            float4 h3 = hi_l[pb + 3];
            float4 res;
            // px 0,1
            {
                h2 xa[4] = { __builtin_bit_cast(h2, h0.x), __builtin_bit_cast(h2, h0.y),
                             __builtin_bit_cast(h2, h0.z), __builtin_bit_cast(h2, h0.w) };
                h2 xb[4] = { __builtin_bit_cast(h2, h1.x), __builtin_bit_cast(h2, h1.y),
                             __builtin_bit_cast(h2, h1.z), __builtin_bit_cast(h2, h1.w) };
                h2 ya[4], yb[4], za[4], zb[4];
                layer8(w1r, b1f, xa, ya);
                layer8(w1r, b1f, xb, yb);
                layer8(w2r, b2f, ya, za);
                layer8(w2r, b2f, yb, zb);
                res.x = layer_out(w3r, b3v, za);
                res.y = layer_out(w3r, b3v, zb);
            }
            // px 2,3
            {
                h2 xa[4] = { __builtin_bit_cast(h2, h2v.x), __builtin_bit_cast(h2, h2v.y),
                             __builtin_bit_cast(h2, h2v.z), __builtin_bit_cast(h2, h2v.w) };
                h2 xb[4] = { __builtin_bit_cast(h2, h3.x), __builtin_bit_cast(h2, h3.y),
                             __builtin_bit_cast(h2, h3.z), __builtin_bit_cast(h2, h3.w) };
                h2 ya[4], yb[4], za[4], zb[4];
                layer8(w1r, b1f, xa, ya);
                layer8(w1r, b1f, xb, yb);
                layer8(w2r, b2f, ya, za);
                layer8(w2r, b2f, yb, zb);
                res.z = layer_out(w3r, b3v, za);
                res.w = layer_out(w3r, b3v, zb);
            }
            *(float4*)(cp + pb) = res;
        }
    }
}

// ---------------- launch ----------------
extern "C" void kernel_launch(void* const* d_in, const int* in_sizes, int n_in,
                              void* d_out, int out_size, void* d_ws, size_t ws_size,
                              hipStream_t stream) {
    const float* dec4         = (const float*)d_in[0];
    const float* feat         = (const float*)d_in[1];
    const float* gn_pre_gamma = (const float*)d_in[2];
    const float* gn_pre_beta  = (const float*)d_in[3];
    const float* W_pre        = (const float*)d_in[4];
    const float* b_pre        = (const float*)d_in[5];
    const float* gn_gap_gamma = (const float*)d_in[6];
    const float* gn_gap_beta  = (const float*)d_in[7];
    const float* W_gap        = (const float*)d_in[8];
    const float* b_gap        = (const float*)d_in[9];
    const float* emb          = (const float*)d_in[10];
    const float* W_ctrl       = (const float*)d_in[11];
    const float* b_ctrl       = (const float*)d_in[12];
    float* out = (float*)d_out;
    float* ws  = (float*)d_ws;

    float* partials = ws;            // 4096 floats (2048 x 2)
    float* g_buf    = ws + 4096;     // 2048
    float* E_ws     = ws + 6144;     // 4896
    unsigned char* pkB = (unsigned char*)(ws + 11040);  // 40960 B (16B-aligned)

    prep<<<2144, 256, 0, stream>>>(feat, dec4, gn_gap_gamma, gn_gap_beta,
                                   emb, W_ctrl, partials, g_buf, E_ws);
    fc<<<4, 256, 0, stream>>>(g_buf, W_gap, b_gap, W_ctrl, b_ctrl, E_ws, pkB);
    mainK<<<512, 512, 0, stream>>>(feat, partials, gn_pre_gamma, gn_pre_beta,
                                   W_pre, b_pre, (const float4*)pkB, out);
}